// Round 6
// baseline (111.969 us; speedup 1.0000x reference)
//
#include <hip/hip_runtime.h>
#include <hip/hip_bf16.h>

// MaskedSelfAttention: B=2, S=2048, D=1024, H=16, depth=64.
// prep (convert+transpose) -> fused QKV GEMM -> flash attn (anti-causal:
// valid k>q; q=2047 row = mean(V) via vmean) -> out GEMM.
// R6: attn T3+T4 — 3-buffer K/V staging (prefetch depth 2) with counted
// s_waitcnt vmcnt(4) + raw s_barrier: staging loads stay in flight across
// the barrier instead of drain-to-zero each iter.

using bf16   = __bf16;
using bf16x2 = __attribute__((ext_vector_type(2))) __bf16;
using bf16x4 = __attribute__((ext_vector_type(4))) __bf16;
using bf16x8 = __attribute__((ext_vector_type(8))) __bf16;
using f32x4  = __attribute__((ext_vector_type(4))) float;
using uintx2 = __attribute__((ext_vector_type(2))) unsigned int;
using uintx4 = __attribute__((ext_vector_type(4))) unsigned int;

__device__ __forceinline__ void load_lds16(const void* g, void* l) {
  __builtin_amdgcn_global_load_lds(
      (const __attribute__((address_space(1))) void*)g,
      (__attribute__((address_space(3))) void*)l, 16, 0, 0);
}

__device__ __forceinline__ unsigned int packbf(float a, float b) {
  bf16x2 v;
  v[0] = (bf16)a;
  v[1] = (bf16)b;
  return __builtin_bit_cast(unsigned int, v);
}

// Redistribute packed P words across hi-groups:
// inputs u,v = own-lane W[2ks][p], W[2ks+1][p]; outputs f,s = pA words m=p, m=2+p.
__device__ __forceinline__ void xchg_p(unsigned int u, unsigned int v, int hi,
                                       unsigned int& f, unsigned int& s) {
#if __has_builtin(__builtin_amdgcn_permlane32_swap) && \
    __has_builtin(__builtin_amdgcn_permlane16_swap)
  uintx2 ab = __builtin_amdgcn_permlane32_swap(u, v, false, false);
  uintx2 fs = __builtin_amdgcn_permlane16_swap(ab[0], ab[1], false, false);
  f = fs[0];
  s = fs[1];
#else
  unsigned int a = (hi < 2) ? u : (unsigned int)__shfl_xor((int)v, 32);
  unsigned int b = (hi < 2) ? (unsigned int)__shfl_xor((int)u, 32) : v;
  unsigned int a16 = (unsigned int)__shfl_xor((int)a, 16);
  unsigned int b16 = (unsigned int)__shfl_xor((int)b, 16);
  f = (hi & 1) ? b16 : a;
  s = (hi & 1) ? b : a16;
#endif
}

// ---------------- prep: convert x + transpose 4 weights ----------------
__global__ __launch_bounds__(256) void prep_kernel(
    const float* __restrict__ x, bf16* __restrict__ xb,
    const float* __restrict__ wq, const float* __restrict__ wk,
    const float* __restrict__ wv, const float* __restrict__ wo,
    bf16* __restrict__ wT) {
  const int t = threadIdx.x;
  int bid = blockIdx.x;
  if (bid < 4096) {  // convert x: f32 -> bf16
    const int i = (bid * 256 + t) * 4;
    const float4 v = *(const float4*)(x + i);
    bf16x4 o;
    o[0] = (bf16)v.x; o[1] = (bf16)v.y; o[2] = (bf16)v.z; o[3] = (bf16)v.w;
    *(bf16x4*)(xb + i) = o;
    return;
  }
  bid -= 4096;
  const int sel = bid >> 8;  // 0..3 : wq wk wv wo
  const float* w = (sel == 0) ? wq : (sel == 1) ? wk : (sel == 2) ? wv : wo;
  bf16* out = wT + (size_t)sel * 1048576;
  __shared__ float tile[64][65];
  const int n0 = (bid & 15) * 64;
  const int k0 = ((bid >> 4) & 15) * 64;
#pragma unroll
  for (int p = 0; p < 4; ++p) {
    const int row = p * 16 + (t >> 4);
    const int c4  = (t & 15) * 4;
    const float4 v = *(const float4*)&w[(size_t)(k0 + row) * 1024 + n0 + c4];
    tile[row][c4 + 0] = v.x; tile[row][c4 + 1] = v.y;
    tile[row][c4 + 2] = v.z; tile[row][c4 + 3] = v.w;
  }
  __syncthreads();
#pragma unroll
  for (int p = 0; p < 4; ++p) {
    const int rn = p * 16 + (t >> 4);
    const int c4 = (t & 15) * 4;
    bf16x4 o;
#pragma unroll
    for (int j = 0; j < 4; ++j) o[j] = (bf16)tile[c4 + j][rn];
    *(bf16x4*)&out[(size_t)(n0 + rn) * 1024 + k0 + c4] = o;
  }
}

// ---------------- GEMM C = A[M][1024] * Bt[N][1024]^T ----------------
template <int MODE>
__global__ __launch_bounds__(256, 2) void gemm_bt(
    const bf16* __restrict__ A, const bf16* __restrict__ Bt,
    const float* __restrict__ bias0, const float* __restrict__ bias1,
    const float* __restrict__ bias2, bf16* __restrict__ qf,
    bf16* __restrict__ kf, bf16* __restrict__ vt, float* __restrict__ fout,
    int Nblocks) {
  __shared__ __align__(16) char smem[32768];
  char* sA = smem;
  char* sB = smem + 16384;
  const int tid = threadIdx.x;
  const int lane = tid & 63;
  const int w = tid >> 6;
  const int wm = w >> 1, wn = w & 1;
  const int bid = blockIdx.x;
  const int m0 = (bid / Nblocks) * 128;
  const int n0 = (bid % Nblocks) * 128;

  const char* Ab = (const char*)A;
  const char* Bb = (const char*)Bt;
  size_t srcA[4], srcB[4];
#pragma unroll
  for (int it = 0; it < 4; ++it) {
    const int o = it * 4096 + tid * 16;
    const int r = o >> 7;
    const int cg = ((o >> 4) & 7) ^ (r & 7);
    srcA[it] = (size_t)(m0 + r) * 2048 + cg * 16;
    srcB[it] = (size_t)(n0 + r) * 2048 + cg * 16;
  }

  f32x4 acc[4][4] = {};

  for (int kt = 0; kt < 16; ++kt) {
    const size_t kb = (size_t)kt * 128;
#pragma unroll
    for (int it = 0; it < 4; ++it) {
      load_lds16(Ab + srcA[it] + kb, sA + it * 4096 + w * 1024);
      load_lds16(Bb + srcB[it] + kb, sB + it * 4096 + w * 1024);
    }
    asm volatile("s_waitcnt vmcnt(0)" ::: "memory");
    __syncthreads();
#pragma unroll
    for (int ks = 0; ks < 2; ++ks) {
      bf16x8 aF[4], bF[4];
      const int g = (lane >> 4) + 4 * ks;
#pragma unroll
      for (int i = 0; i < 4; ++i) {
        const int ra = wm * 64 + i * 16 + (lane & 15);
        aF[i] = *(const bf16x8*)(sA + ra * 128 + ((g ^ (ra & 7)) << 4));
        const int rb = wn * 64 + i * 16 + (lane & 15);
        bF[i] = *(const bf16x8*)(sB + rb * 128 + ((g ^ (rb & 7)) << 4));
      }
#pragma unroll
      for (int mi = 0; mi < 4; ++mi)
#pragma unroll
        for (int ni = 0; ni < 4; ++ni)
          acc[mi][ni] = __builtin_amdgcn_mfma_f32_16x16x32_bf16(
              aF[mi], bF[ni], acc[mi][ni], 0, 0, 0);
    }
    __syncthreads();
  }

  const int cn = lane & 15;
  const int gq = lane >> 4;
#pragma unroll
  for (int mi = 0; mi < 4; ++mi) {
#pragma unroll
    for (int ni = 0; ni < 4; ++ni) {
      const int n  = n0 + wn * 64 + ni * 16 + cn;
      const int mb = m0 + wm * 64 + mi * 16 + 4 * gq;
      const f32x4 v = acc[mi][ni];
      if (MODE == 0) {
        const float bias =
            (n < 1024) ? bias0[n] : ((n < 2048) ? bias1[n - 1024] : bias2[n - 2048]);
        if (n < 2048) {
          bf16* dst = (n < 1024) ? qf : kf;
          const int nn = n & 1023;
#pragma unroll
          for (int j = 0; j < 4; ++j)
            dst[(size_t)(mb + j) * 1024 + nn] = (bf16)(v[j] + bias);
        } else {
          const int nn = n - 2048;
          const int hh = nn >> 6, dd = nn & 63;
          const int bb = mb >> 11, ss = mb & 2047;
          bf16x4 pk;
#pragma unroll
          for (int j = 0; j < 4; ++j) pk[j] = (bf16)(v[j] + bias);
          *(bf16x4*)(vt + ((size_t)((bb * 16 + hh) * 64 + dd) * 2048 + ss)) = pk;
        }
      } else {
        const float bias = bias0[n];
#pragma unroll
        for (int j = 0; j < 4; ++j)
          fout[(size_t)(mb + j) * 1024 + n] = v[j] + bias;
      }
    }
  }
}

// ---------------- flash attention v6 (valid keys: k > q) ----------------
// 512 blocks = 16 q-tiles (128 rows) x 32 bh; heavy/light complementary
// ordering. 4 waves x 32 q-rows; in-register P. NEW: 3-buffer K/V staging,
// prefetch depth 2, counted s_waitcnt vmcnt(4) + raw s_barrier -> staging
// loads stay in flight across iteration boundaries (no drain-to-zero).
__global__ __launch_bounds__(256, 2) void attn_kernel(
    const bf16* __restrict__ qf, const bf16* __restrict__ kf,
    const bf16* __restrict__ vt, bf16* __restrict__ ao) {
  // buf i (i=0..2): K at i*16384 (8 KB), V at i*16384+8192 (8 KB)
  __shared__ __align__(16) char smem[49152];

  const int tid  = threadIdx.x;
  const int lane = tid & 63;
  const int hi   = lane >> 4;
  const int qlo  = lane & 15;
  const int w    = tid >> 6;
  const int ti = blockIdx.x >> 5;        // 0..15
  const int jq = (ti < 8) ? ti : 23 - ti;
  const int bh = blockIdx.x & 31;        // same-bh blocks share an XCD's L2
  const int b = bh >> 4, h = bh & 15;

  const char* kbase = (const char*)kf + ((size_t)b * 2048) * 2048 + h * 128;
  const char* vbase = (const char*)vt + (size_t)bh * 262144;
  const char* qbb   = (const char*)qf + ((size_t)b * 2048) * 2048 + h * 128;

  const int sr  = tid >> 3;              // staging row 0..31 (pass 2: +32)
  const int scg = (tid & 7) ^ (sr & 7);  // pre-swizzled source chunk

  bf16x8 onesB;
#pragma unroll
  for (int i = 0; i < 8; ++i) onesB[i] = (bf16)1.0f;

  const int q0 = jq * 128;
  const int qb = q0 + w * 32;

  // Q fragments for 2 column-tiles (pre-scaled by 1/8 -- exact in bf16)
  bf16x8 qA[2][2];
#pragma unroll
  for (int nt = 0; nt < 2; ++nt) {
    const char* qrow = qbb + (size_t)(qb + 16 * nt + qlo) * 2048;
#pragma unroll
    for (int ks = 0; ks < 2; ++ks) {
      qA[nt][ks] = *(const bf16x8*)(qrow + ks * 64 + hi * 16);
#pragma unroll
      for (int i = 0; i < 8; ++i)
        qA[nt][ks][i] = (bf16)(0.125f * (float)qA[nt][ks][i]);
    }
  }

  float m[2] = {-1e30f, -1e30f};
  f32x4 lacc[2] = {};
  f32x4 O[2][4] = {};

  const int nt_tiles = (2048 - q0) >> 6;

  // stage k-tile `kt` (4 global_load_lds per thread -> 4 vmcnt events/wave)
  auto STAGE = [&](int kt, int bufi) {
    char* dK = smem + bufi * 16384 + w * 1024;
    char* dV = smem + bufi * 16384 + 8192 + w * 1024;
    const int kn = q0 + kt * 64;
#pragma unroll
    for (int p = 0; p < 2; ++p) {
      load_lds16(kbase + (size_t)(kn + sr + 32 * p) * 2048 + scg * 16,
                 dK + p * 4096);
      load_lds16(vbase + (size_t)(sr + 32 * p) * 4096 + (size_t)kn * 2 +
                     scg * 16,
                 dV + p * 4096);
    }
  };

  // prologue: prefetch tiles 0 and 1; wait only for tile 0 (vmcnt(4))
  STAGE(0, 0);
  if (nt_tiles > 1) {
    STAGE(1, 1);
    asm volatile("s_waitcnt vmcnt(4)" ::: "memory");
  } else {
    asm volatile("s_waitcnt vmcnt(0)" ::: "memory");
  }
  __builtin_amdgcn_s_barrier();

  int cur = 0;
  for (int it = 0; it < nt_tiles; ++it) {
    // issue stage(t+2) into the buffer freed after iter t-1
    if (it + 2 < nt_tiles) {
      int bufi = cur + 2;
      if (bufi >= 3) bufi -= 3;
      STAGE(it + 2, bufi);
    }
    const char* bK = smem + cur * 16384;
    const char* bV = smem + cur * 16384 + 8192;

    // QK^T swapped: sc[nt][t] rows = k (16t+4hi+j), col = q (16nt+qlo);
    // kF shared across both nt tiles.
    f32x4 sc[2][4] = {};
#pragma unroll
    for (int ks = 0; ks < 2; ++ks) {
      const int g = hi + 4 * ks;
#pragma unroll
      for (int t = 0; t < 4; ++t) {
        const int rk = t * 16 + qlo;
        const bf16x8 kF =
            *(const bf16x8*)(bK + rk * 128 + ((g ^ (rk & 7)) << 4));
        sc[0][t] = __builtin_amdgcn_mfma_f32_16x16x32_bf16(kF, qA[0][ks],
                                                           sc[0][t], 0, 0, 0);
        sc[1][t] = __builtin_amdgcn_mfma_f32_16x16x32_bf16(kF, qA[1][ks],
                                                           sc[1][t], 0, 0, 0);
      }
    }

    if (it < 2) {  // tiles overlapping the q-range: mask k <= q
      const int k0t = q0 + it * 64;
#pragma unroll
      for (int nt = 0; nt < 2; ++nt)
#pragma unroll
        for (int t = 0; t < 4; ++t)
#pragma unroll
          for (int j = 0; j < 4; ++j) {
            const int kk = k0t + t * 16 + 4 * hi + j;
            const int qq = qb + 16 * nt + qlo;
            if (kk <= qq) sc[nt][t][j] = -1e30f;
          }
    }

    // per-q tile max (lane-local 16 vals + 2 shfl)
    float tm[2];
#pragma unroll
    for (int nt = 0; nt < 2; ++nt) {
      float v = sc[nt][0][0];
#pragma unroll
      for (int t = 0; t < 4; ++t)
#pragma unroll
        for (int j = 0; j < 4; ++j) v = fmaxf(v, sc[nt][t][j]);
      v = fmaxf(v, __shfl_xor(v, 16));
      v = fmaxf(v, __shfl_xor(v, 32));
      tm[nt] = v;
    }

    // T13 defer-max: rescale only when some row's max grew by > 8
    const bool grew = (tm[0] - m[0] > 8.0f) || (tm[1] - m[1] > 8.0f);
    if (__any(grew)) {
#pragma unroll
      for (int nt = 0; nt < 2; ++nt) {
        const float mn = fmaxf(m[nt], tm[nt]);
        const float al = __expf(m[nt] - mn);
        m[nt] = mn;
#pragma unroll
        for (int j = 0; j < 4; ++j) {
          const float alj = __shfl(al, 4 * hi + j);
          lacc[nt][j] *= alj;
#pragma unroll
          for (int dt = 0; dt < 4; ++dt) O[nt][dt][j] *= alj;
        }
      }
    }

    // P = exp(s - m) packed to bf16 pairs, redistributed in-register to
    // the PV A-fragment layout (no LDS round-trip).
    bf16x8 pA[2][2];
#pragma unroll
    for (int nt = 0; nt < 2; ++nt) {
      unsigned int W[4][2];
#pragma unroll
      for (int t = 0; t < 4; ++t)
#pragma unroll
        for (int p = 0; p < 2; ++p)
          W[t][p] = packbf(__expf(sc[nt][t][2 * p] - m[nt]),
                           __expf(sc[nt][t][2 * p + 1] - m[nt]));
#pragma unroll
      for (int ks = 0; ks < 2; ++ks) {
        uintx4 w4;
#pragma unroll
        for (int p = 0; p < 2; ++p) {
          unsigned int f, s;
          xchg_p(W[2 * ks][p], W[2 * ks + 1][p], hi, f, s);
          w4[p] = f;
          w4[2 + p] = s;
        }
        pA[nt][ks] = __builtin_bit_cast(bf16x8, w4);
        lacc[nt] = __builtin_amdgcn_mfma_f32_16x16x32_bf16(pA[nt][ks], onesB,
                                                           lacc[nt], 0, 0, 0);
      }
    }

    // PV: O[q][d] += P*V ; vF shared across both nt tiles
#pragma unroll
    for (int ks = 0; ks < 2; ++ks) {
      const int g = hi + 4 * ks;
#pragma unroll
      for (int dt = 0; dt < 4; ++dt) {
        const int rv = dt * 16 + qlo;
        const bf16x8 vF =
            *(const bf16x8*)(bV + rv * 128 + ((g ^ (rv & 7)) << 4));
        O[0][dt] = __builtin_amdgcn_mfma_f32_16x16x32_bf16(pA[0][ks], vF,
                                                           O[0][dt], 0, 0, 0);
        O[1][dt] = __builtin_amdgcn_mfma_f32_16x16x32_bf16(pA[1][ks], vF,
                                                           O[1][dt], 0, 0, 0);
      }
    }

    // iteration boundary: drain ONLY stage(t+1); stage(t+2) stays in flight
    if (it + 1 < nt_tiles) {
      if (it + 2 < nt_tiles)
        asm volatile("s_waitcnt vmcnt(4)" ::: "memory");
      else
        asm volatile("s_waitcnt vmcnt(0)" ::: "memory");
      __builtin_amdgcn_s_barrier();
    }
    ++cur;
    if (cur >= 3) cur = 0;
  }

  // epilogue: O rows (4*hi+j) and lacc rows match -> all lane-local
#pragma unroll
  for (int nt = 0; nt < 2; ++nt)
#pragma unroll
    for (int j = 0; j < 4; ++j) {
      const float linv = (lacc[nt][j] > 0.f) ? 1.f / lacc[nt][j] : 0.f;
      const int qg = qb + 16 * nt + 4 * hi + j;
#pragma unroll
      for (int dt = 0; dt < 4; ++dt)
        ao[(size_t)(b * 2048 + qg) * 1024 + h * 64 + dt * 16 + qlo] =
            (bf16)(O[nt][dt][j] * linv);
    }
}

// ---------------- last-row fix: ao[q=2047] = mean over s of V ----------------
__global__ __launch_bounds__(256) void vmean_kernel(const bf16* __restrict__ vt,
                                                    bf16* __restrict__ ao) {
  const int tid = threadIdx.x;
  const int lane = tid & 63, w = tid >> 6;
  const int gw = blockIdx.x * 4 + w;  // 0..2047 == bh*64 + d
  const int bh = gw >> 6, d = gw & 63;
  const int b = bh >> 4, h = bh & 15;
  const bf16x8* p = (const bf16x8*)(vt + (size_t)gw * 2048 + lane * 32);
  float s = 0.f;
#pragma unroll
  for (int i = 0; i < 4; ++i) {
    const bf16x8 v = p[i];
#pragma unroll
    for (int j = 0; j < 8; ++j) s += (float)v[j];
  }
  for (int off = 1; off < 64; off <<= 1) s += __shfl_xor(s, off);
  if (lane == 0)
    ao[(size_t)(b * 2048 + 2047) * 1024 + h * 64 + d] = (bf16)(s * (1.f / 2048.f));
}

extern "C" void kernel_launch(void* const* d_in, const int* in_sizes, int n_in,
                              void* d_out, int out_size, void* d_ws,
                              size_t ws_size, hipStream_t stream) {
  const float* x  = (const float*)d_in[0];
  const float* wq = (const float*)d_in[2];
  const float* bq = (const float*)d_in[3];
  const float* wk = (const float*)d_in[4];
  const float* bk = (const float*)d_in[5];
  const float* wv = (const float*)d_in[6];
  const float* bv = (const float*)d_in[7];
  const float* wo = (const float*)d_in[8];
  const float* bo = (const float*)d_in[9];
  float* out = (float*)d_out;

  if (ws_size < (size_t)25165824 * 2) return;  // need ~48 MiB of scratch

  bf16* ws    = (bf16*)d_ws;
  bf16* xb    = ws;                     // [4096][1024]
  bf16* wqkvT = xb + 4194304;           // [3072][1024]
  bf16* woT   = wqkvT + 3145728;        // [1024][1024]  (contiguous after)
  bf16* qfp   = woT + 1048576;          // [4096][1024] flat
  bf16* kfp   = qfp + 4194304;          // [4096][1024] flat
  bf16* vtp   = kfp + 4194304;          // [b][h][d][s]
  bf16* aop   = vtp + 4194304;          // [4096][1024] flat

  prep_kernel<<<5120, 256, 0, stream>>>(x, xb, wq, wk, wv, wo, wqkvT);

  gemm_bt<0><<<32 * 24, 256, 0, stream>>>(xb, wqkvT, bq, bk, bv, qfp, kfp, vtp,
                                          nullptr, 24);
  attn_kernel<<<512, 256, 0, stream>>>(qfp, kfp, vtp, aop);
  vmean_kernel<<<512, 256, 0, stream>>>(vtp, aop);
  gemm_bt<1><<<32 * 8, 256, 0, stream>>>(aop, woT, bo, nullptr, nullptr, nullptr,
                                         nullptr, nullptr, out, 8);
}

// Round 7
// 106.907 us; speedup vs baseline: 1.0474x; 1.0474x over previous
//
#include <hip/hip_runtime.h>
#include <hip/hip_bf16.h>

// MaskedSelfAttention: B=2, S=2048, D=1024, H=16, depth=64.
// prep (convert+transpose) -> fused QKV GEMM -> flash attn (anti-causal:
// valid k>q; q=2047 row = mean(V) via vmean) -> combine -> out GEMM.
// R7: attn load balance — 768 uniform work units (heavy q-tiles jq=0..7
// split into two k-chunks with flash partials; light whole), dispatch
// triples sum to 34 iters/CU. Partials: O1 in aop rows, O2+m/l in xb
// (free after QKV GEMM). Cheap combine kernel. 2-buffer staging (R5).

using bf16   = __bf16;
using bf16x2 = __attribute__((ext_vector_type(2))) __bf16;
using bf16x4 = __attribute__((ext_vector_type(4))) __bf16;
using bf16x8 = __attribute__((ext_vector_type(8))) __bf16;
using f32x4  = __attribute__((ext_vector_type(4))) float;
using uintx2 = __attribute__((ext_vector_type(2))) unsigned int;
using uintx4 = __attribute__((ext_vector_type(4))) unsigned int;

__device__ __forceinline__ void load_lds16(const void* g, void* l) {
  __builtin_amdgcn_global_load_lds(
      (const __attribute__((address_space(1))) void*)g,
      (__attribute__((address_space(3))) void*)l, 16, 0, 0);
}

__device__ __forceinline__ unsigned int packbf(float a, float b) {
  bf16x2 v;
  v[0] = (bf16)a;
  v[1] = (bf16)b;
  return __builtin_bit_cast(unsigned int, v);
}

// Redistribute packed P words across hi-groups (in-register P, R4).
__device__ __forceinline__ void xchg_p(unsigned int u, unsigned int v, int hi,
                                       unsigned int& f, unsigned int& s) {
#if __has_builtin(__builtin_amdgcn_permlane32_swap) && \
    __has_builtin(__builtin_amdgcn_permlane16_swap)
  uintx2 ab = __builtin_amdgcn_permlane32_swap(u, v, false, false);
  uintx2 fs = __builtin_amdgcn_permlane16_swap(ab[0], ab[1], false, false);
  f = fs[0];
  s = fs[1];
#else
  unsigned int a = (hi < 2) ? u : (unsigned int)__shfl_xor((int)v, 32);
  unsigned int b = (hi < 2) ? (unsigned int)__shfl_xor((int)u, 32) : v;
  unsigned int a16 = (unsigned int)__shfl_xor((int)a, 16);
  unsigned int b16 = (unsigned int)__shfl_xor((int)b, 16);
  f = (hi & 1) ? b16 : a;
  s = (hi & 1) ? b : a16;
#endif
}

// ---------------- prep: convert x + transpose 4 weights ----------------
__global__ __launch_bounds__(256) void prep_kernel(
    const float* __restrict__ x, bf16* __restrict__ xb,
    const float* __restrict__ wq, const float* __restrict__ wk,
    const float* __restrict__ wv, const float* __restrict__ wo,
    bf16* __restrict__ wT) {
  const int t = threadIdx.x;
  int bid = blockIdx.x;
  if (bid < 4096) {  // convert x: f32 -> bf16
    const int i = (bid * 256 + t) * 4;
    const float4 v = *(const float4*)(x + i);
    bf16x4 o;
    o[0] = (bf16)v.x; o[1] = (bf16)v.y; o[2] = (bf16)v.z; o[3] = (bf16)v.w;
    *(bf16x4*)(xb + i) = o;
    return;
  }
  bid -= 4096;
  const int sel = bid >> 8;  // 0..3 : wq wk wv wo
  const float* w = (sel == 0) ? wq : (sel == 1) ? wk : (sel == 2) ? wv : wo;
  bf16* out = wT + (size_t)sel * 1048576;
  __shared__ float tile[64][65];
  const int n0 = (bid & 15) * 64;
  const int k0 = ((bid >> 4) & 15) * 64;
#pragma unroll
  for (int p = 0; p < 4; ++p) {
    const int row = p * 16 + (t >> 4);
    const int c4  = (t & 15) * 4;
    const float4 v = *(const float4*)&w[(size_t)(k0 + row) * 1024 + n0 + c4];
    tile[row][c4 + 0] = v.x; tile[row][c4 + 1] = v.y;
    tile[row][c4 + 2] = v.z; tile[row][c4 + 3] = v.w;
  }
  __syncthreads();
#pragma unroll
  for (int p = 0; p < 4; ++p) {
    const int rn = p * 16 + (t >> 4);
    const int c4 = (t & 15) * 4;
    bf16x4 o;
#pragma unroll
    for (int j = 0; j < 4; ++j) o[j] = (bf16)tile[c4 + j][rn];
    *(bf16x4*)&out[(size_t)(n0 + rn) * 1024 + k0 + c4] = o;
  }
}

// ---------------- GEMM C = A[M][1024] * Bt[N][1024]^T ----------------
template <int MODE>
__global__ __launch_bounds__(256, 2) void gemm_bt(
    const bf16* __restrict__ A, const bf16* __restrict__ Bt,
    const float* __restrict__ bias0, const float* __restrict__ bias1,
    const float* __restrict__ bias2, bf16* __restrict__ qf,
    bf16* __restrict__ kf, bf16* __restrict__ vt, float* __restrict__ fout,
    int Nblocks) {
  __shared__ __align__(16) char smem[32768];
  char* sA = smem;
  char* sB = smem + 16384;
  const int tid = threadIdx.x;
  const int lane = tid & 63;
  const int w = tid >> 6;
  const int wm = w >> 1, wn = w & 1;
  const int bid = blockIdx.x;
  const int m0 = (bid / Nblocks) * 128;
  const int n0 = (bid % Nblocks) * 128;

  const char* Ab = (const char*)A;
  const char* Bb = (const char*)Bt;
  size_t srcA[4], srcB[4];
#pragma unroll
  for (int it = 0; it < 4; ++it) {
    const int o = it * 4096 + tid * 16;
    const int r = o >> 7;
    const int cg = ((o >> 4) & 7) ^ (r & 7);
    srcA[it] = (size_t)(m0 + r) * 2048 + cg * 16;
    srcB[it] = (size_t)(n0 + r) * 2048 + cg * 16;
  }

  f32x4 acc[4][4] = {};

  for (int kt = 0; kt < 16; ++kt) {
    const size_t kb = (size_t)kt * 128;
#pragma unroll
    for (int it = 0; it < 4; ++it) {
      load_lds16(Ab + srcA[it] + kb, sA + it * 4096 + w * 1024);
      load_lds16(Bb + srcB[it] + kb, sB + it * 4096 + w * 1024);
    }
    asm volatile("s_waitcnt vmcnt(0)" ::: "memory");
    __syncthreads();
#pragma unroll
    for (int ks = 0; ks < 2; ++ks) {
      bf16x8 aF[4], bF[4];
      const int g = (lane >> 4) + 4 * ks;
#pragma unroll
      for (int i = 0; i < 4; ++i) {
        const int ra = wm * 64 + i * 16 + (lane & 15);
        aF[i] = *(const bf16x8*)(sA + ra * 128 + ((g ^ (ra & 7)) << 4));
        const int rb = wn * 64 + i * 16 + (lane & 15);
        bF[i] = *(const bf16x8*)(sB + rb * 128 + ((g ^ (rb & 7)) << 4));
      }
#pragma unroll
      for (int mi = 0; mi < 4; ++mi)
#pragma unroll
        for (int ni = 0; ni < 4; ++ni)
          acc[mi][ni] = __builtin_amdgcn_mfma_f32_16x16x32_bf16(
              aF[mi], bF[ni], acc[mi][ni], 0, 0, 0);
    }
    __syncthreads();
  }

  const int cn = lane & 15;
  const int gq = lane >> 4;
#pragma unroll
  for (int mi = 0; mi < 4; ++mi) {
#pragma unroll
    for (int ni = 0; ni < 4; ++ni) {
      const int n  = n0 + wn * 64 + ni * 16 + cn;
      const int mb = m0 + wm * 64 + mi * 16 + 4 * gq;
      const f32x4 v = acc[mi][ni];
      if (MODE == 0) {
        const float bias =
            (n < 1024) ? bias0[n] : ((n < 2048) ? bias1[n - 1024] : bias2[n - 2048]);
        if (n < 2048) {
          bf16* dst = (n < 1024) ? qf : kf;
          const int nn = n & 1023;
#pragma unroll
          for (int j = 0; j < 4; ++j)
            dst[(size_t)(mb + j) * 1024 + nn] = (bf16)(v[j] + bias);
        } else {
          const int nn = n - 2048;
          const int hh = nn >> 6, dd = nn & 63;
          const int bb = mb >> 11, ss = mb & 2047;
          bf16x4 pk;
#pragma unroll
          for (int j = 0; j < 4; ++j) pk[j] = (bf16)(v[j] + bias);
          *(bf16x4*)(vt + ((size_t)((bb * 16 + hh) * 64 + dd) * 2048 + ss)) = pk;
        }
      } else {
        const float bias = bias0[n];
#pragma unroll
        for (int j = 0; j < 4; ++j)
          fout[(size_t)(mb + j) * 1024 + n] = v[j] + bias;
      }
    }
  }
}

// ---------------- flash attention v7 (valid keys: k > q) ----------------
// 768 blocks = 24 units x 32 bh. Unit table: heavy q-tiles jq=0..7 split
// into two k-chunks (modes 1,2 -> flash partials); light jq=8..15 whole
// (mode 0 -> normalized write). Dispatch triples (c, c+256, c+512) each sum
// to 34 iters -> uniform per-CU work at 3 blocks/CU. 4 waves x 32 q-rows,
// in-register P, 2-buffer staging.
__global__ __launch_bounds__(256, 3) void attn_kernel(
    const bf16* __restrict__ qf, const bf16* __restrict__ kf,
    const bf16* __restrict__ vt, bf16* __restrict__ ao,
    bf16* __restrict__ o2buf, float* __restrict__ mlbuf) {
  __shared__ __align__(16) char smem[32768];  // sK[2][8192] | sV[2][8192]

  // unit table: jq | kbeg<<8 | kend<<16 | mode<<24
  const unsigned int TAB[24] = {
      0u | (0u << 8)  | (16u << 16) | (1u << 24),
      0u | (16u << 8) | (32u << 16) | (2u << 24),
      1u | (2u << 8)  | (17u << 16) | (1u << 24),
      1u | (17u << 8) | (32u << 16) | (2u << 24),
      2u | (4u << 8)  | (18u << 16) | (1u << 24),
      2u | (18u << 8) | (32u << 16) | (2u << 24),
      3u | (6u << 8)  | (19u << 16) | (1u << 24),
      4u | (8u << 8)  | (20u << 16) | (1u << 24),
      8u | (16u << 8) | (32u << 16) | (0u << 24),
      9u | (18u << 8) | (32u << 16) | (0u << 24),
      3u | (19u << 8) | (32u << 16) | (2u << 24),
      5u | (10u << 8) | (21u << 16) | (1u << 24),
      5u | (21u << 8) | (32u << 16) | (2u << 24),
      6u | (12u << 8) | (22u << 16) | (1u << 24),
      4u | (20u << 8) | (32u << 16) | (2u << 24),
      10u | (20u << 8) | (32u << 16) | (0u << 24),
      15u | (30u << 8) | (32u << 16) | (0u << 24),
      14u | (28u << 8) | (32u << 16) | (0u << 24),
      13u | (26u << 8) | (32u << 16) | (0u << 24),
      12u | (24u << 8) | (32u << 16) | (0u << 24),
      7u | (14u << 8) | (23u << 16) | (1u << 24),
      6u | (22u << 8) | (32u << 16) | (2u << 24),
      7u | (23u << 8) | (32u << 16) | (2u << 24),
      11u | (22u << 8) | (32u << 16) | (0u << 24)};

  const int tid  = threadIdx.x;
  const int lane = tid & 63;
  const int hi   = lane >> 4;
  const int qlo  = lane & 15;
  const int w    = tid >> 6;
  const int u  = blockIdx.x >> 5;
  const int bh = blockIdx.x & 31;  // same-bh blocks share an XCD's L2
  const int b = bh >> 4, h = bh & 15;
  const unsigned int ent = TAB[u];
  const int jq = ent & 255, kbeg = (ent >> 8) & 255, kend = (ent >> 16) & 255;
  const int mode = ent >> 24;

  const char* kbase = (const char*)kf + ((size_t)b * 2048) * 2048 + h * 128;
  const char* vbase = (const char*)vt + (size_t)bh * 262144;
  const char* qbb   = (const char*)qf + ((size_t)b * 2048) * 2048 + h * 128;

  const int sr  = tid >> 3;              // staging row 0..31 (pass 2: +32)
  const int scg = (tid & 7) ^ (sr & 7);  // pre-swizzled source chunk

  bf16x8 onesB;
#pragma unroll
  for (int i = 0; i < 8; ++i) onesB[i] = (bf16)1.0f;

  const int q0 = jq * 128;
  const int qb = q0 + w * 32;

  // Q fragments for 2 column-tiles (pre-scaled by 1/8 -- exact in bf16)
  bf16x8 qA[2][2];
#pragma unroll
  for (int nt = 0; nt < 2; ++nt) {
    const char* qrow = qbb + (size_t)(qb + 16 * nt + qlo) * 2048;
#pragma unroll
    for (int ks = 0; ks < 2; ++ks) {
      qA[nt][ks] = *(const bf16x8*)(qrow + ks * 64 + hi * 16);
#pragma unroll
      for (int i = 0; i < 8; ++i)
        qA[nt][ks][i] = (bf16)(0.125f * (float)qA[nt][ks][i]);
    }
  }

  float m[2] = {-1e30f, -1e30f};
  f32x4 lacc[2] = {};
  f32x4 O[2][4] = {};

  // stage absolute k-tile kt into buffer bufi
  auto STAGE = [&](int kt, int bufi) {
    char* dK = smem + bufi * 8192 + w * 1024;
    char* dV = smem + 16384 + bufi * 8192 + w * 1024;
    const int kn = kt * 64;
#pragma unroll
    for (int p = 0; p < 2; ++p) {
      load_lds16(kbase + (size_t)(kn + sr + 32 * p) * 2048 + scg * 16,
                 dK + p * 4096);
      load_lds16(vbase + (size_t)(sr + 32 * p) * 4096 + (size_t)kn * 2 +
                     scg * 16,
                 dV + p * 4096);
    }
  };

  STAGE(kbeg, 0);
  __syncthreads();

  for (int kt = kbeg; kt < kend; ++kt) {
    const int cur = (kt - kbeg) & 1;

    // issue next-tile staging (drains at this iteration's closing barrier)
    if (kt + 1 < kend) STAGE(kt + 1, cur ^ 1);

    const char* bK = smem + cur * 8192;
    const char* bV = smem + 16384 + cur * 8192;

    // QK^T swapped: sc[nt][t] rows = k (16t+4hi+j), col = q (16nt+qlo);
    // kF shared across both nt tiles.
    f32x4 sc[2][4] = {};
#pragma unroll
    for (int ks = 0; ks < 2; ++ks) {
      const int g = hi + 4 * ks;
#pragma unroll
      for (int t = 0; t < 4; ++t) {
        const int rk = t * 16 + qlo;
        const bf16x8 kF =
            *(const bf16x8*)(bK + rk * 128 + ((g ^ (rk & 7)) << 4));
        sc[0][t] = __builtin_amdgcn_mfma_f32_16x16x32_bf16(kF, qA[0][ks],
                                                           sc[0][t], 0, 0, 0);
        sc[1][t] = __builtin_amdgcn_mfma_f32_16x16x32_bf16(kF, qA[1][ks],
                                                           sc[1][t], 0, 0, 0);
      }
    }

    if (kt * 64 < q0 + 128) {  // tiles overlapping the q-range: mask k <= q
      const int k0t = kt * 64;
#pragma unroll
      for (int nt = 0; nt < 2; ++nt)
#pragma unroll
        for (int t = 0; t < 4; ++t)
#pragma unroll
          for (int j = 0; j < 4; ++j) {
            const int kk = k0t + t * 16 + 4 * hi + j;
            const int qq = qb + 16 * nt + qlo;
            if (kk <= qq) sc[nt][t][j] = -1e30f;
          }
    }

    // per-q tile max (lane-local 16 vals + 2 shfl)
    float tm[2];
#pragma unroll
    for (int nt = 0; nt < 2; ++nt) {
      float v = sc[nt][0][0];
#pragma unroll
      for (int t = 0; t < 4; ++t)
#pragma unroll
        for (int j = 0; j < 4; ++j) v = fmaxf(v, sc[nt][t][j]);
      v = fmaxf(v, __shfl_xor(v, 16));
      v = fmaxf(v, __shfl_xor(v, 32));
      tm[nt] = v;
    }

    // T13 defer-max: rescale only when some row's max grew by > 8
    const bool grew = (tm[0] - m[0] > 8.0f) || (tm[1] - m[1] > 8.0f);
    if (__any(grew)) {
#pragma unroll
      for (int nt = 0; nt < 2; ++nt) {
        const float mn = fmaxf(m[nt], tm[nt]);
        const float al = __expf(m[nt] - mn);
        m[nt] = mn;
#pragma unroll
        for (int j = 0; j < 4; ++j) {
          const float alj = __shfl(al, 4 * hi + j);
          lacc[nt][j] *= alj;
#pragma unroll
          for (int dt = 0; dt < 4; ++dt) O[nt][dt][j] *= alj;
        }
      }
    }

    // P = exp(s - m) packed to bf16 pairs, redistributed in-register to
    // the PV A-fragment layout (no LDS round-trip).
    bf16x8 pA[2][2];
#pragma unroll
    for (int nt = 0; nt < 2; ++nt) {
      unsigned int W[4][2];
#pragma unroll
      for (int t = 0; t < 4; ++t)
#pragma unroll
        for (int p = 0; p < 2; ++p)
          W[t][p] = packbf(__expf(sc[nt][t][2 * p] - m[nt]),
                           __expf(sc[nt][t][2 * p + 1] - m[nt]));
#pragma unroll
      for (int ks = 0; ks < 2; ++ks) {
        uintx4 w4;
#pragma unroll
        for (int p = 0; p < 2; ++p) {
          unsigned int f, s;
          xchg_p(W[2 * ks][p], W[2 * ks + 1][p], hi, f, s);
          w4[p] = f;
          w4[2 + p] = s;
        }
        pA[nt][ks] = __builtin_bit_cast(bf16x8, w4);
        lacc[nt] = __builtin_amdgcn_mfma_f32_16x16x32_bf16(pA[nt][ks], onesB,
                                                           lacc[nt], 0, 0, 0);
      }
    }

    // PV: O[q][d] += P*V ; vF shared across both nt tiles
#pragma unroll
    for (int ks = 0; ks < 2; ++ks) {
      const int g = hi + 4 * ks;
#pragma unroll
      for (int dt = 0; dt < 4; ++dt) {
        const int rv = dt * 16 + qlo;
        const bf16x8 vF =
            *(const bf16x8*)(bV + rv * 128 + ((g ^ (rv & 7)) << 4));
        O[0][dt] = __builtin_amdgcn_mfma_f32_16x16x32_bf16(pA[0][ks], vF,
                                                           O[0][dt], 0, 0, 0);
        O[1][dt] = __builtin_amdgcn_mfma_f32_16x16x32_bf16(pA[1][ks], vF,
                                                           O[1][dt], 0, 0, 0);
      }
    }
    __syncthreads();
  }

  if (mode == 0) {
    // normalized write (O rows 4*hi+j; lacc[j] same rows -> lane-local)
#pragma unroll
    for (int nt = 0; nt < 2; ++nt)
#pragma unroll
      for (int j = 0; j < 4; ++j) {
        const float linv = (lacc[nt][j] > 0.f) ? 1.f / lacc[nt][j] : 0.f;
        const int qg = qb + 16 * nt + 4 * hi + j;
#pragma unroll
        for (int dt = 0; dt < 4; ++dt)
          ao[(size_t)(b * 2048 + qg) * 1024 + h * 64 + dt * 16 + qlo] =
              (bf16)(O[nt][dt][j] * linv);
      }
  } else {
    // flash partial write: unnormalized O (bf16) + m,l (f32)
    const int qtbh = jq * 32 + bh;
    const int slot = mode - 1;
#pragma unroll
    for (int nt = 0; nt < 2; ++nt)
#pragma unroll
      for (int j = 0; j < 4; ++j) {
        const int r = w * 32 + 16 * nt + 4 * hi + j;  // row within q-tile
#pragma unroll
        for (int dt = 0; dt < 4; ++dt) {
          const bf16 vv = (bf16)O[nt][dt][j];
          if (mode == 1)
            ao[(size_t)(b * 2048 + q0 + r) * 1024 + h * 64 + dt * 16 + qlo] = vv;
          else
            o2buf[(size_t)(qtbh * 128 + r) * 64 + dt * 16 + qlo] = vv;
        }
      }
    if (qlo == 0) {
#pragma unroll
      for (int nt = 0; nt < 2; ++nt)
#pragma unroll
        for (int j = 0; j < 4; ++j)
          mlbuf[((qtbh * 2 + slot) * 2 + 1) * 128 + (w * 32 + 16 * nt + 4 * hi + j)] =
              lacc[nt][j];
    }
    if (hi == 0) {
#pragma unroll
      for (int nt = 0; nt < 2; ++nt)
        mlbuf[((qtbh * 2 + slot) * 2 + 0) * 128 + (w * 32 + 16 * nt + qlo)] =
            m[nt];
    }
  }
}

// ---------------- combine: merge the two k-chunk partials (jq=0..7) -------
__global__ __launch_bounds__(256) void combine_kernel(
    const bf16* __restrict__ o2buf, const float* __restrict__ mlbuf,
    bf16* __restrict__ ao) {
  const int qtbh = blockIdx.x;  // jq*32 + bh, jq in 0..7
  const int jq = qtbh >> 5, bh = qtbh & 31;
  const int b = bh >> 4, h = bh & 15;
  const int t = threadIdx.x;
  const int r = t >> 1;
  const int c0 = (t & 1) * 32;

  const float m1 = mlbuf[((qtbh * 2 + 0) * 2 + 0) * 128 + r];
  const float l1 = mlbuf[((qtbh * 2 + 0) * 2 + 1) * 128 + r];
  const float m2 = mlbuf[((qtbh * 2 + 1) * 2 + 0) * 128 + r];
  const float l2 = mlbuf[((qtbh * 2 + 1) * 2 + 1) * 128 + r];
  const float M  = fmaxf(m1, m2);
  const float w1 = __expf(m1 - M), w2 = __expf(m2 - M);
  const float denom = w1 * l1 + w2 * l2;
  const float linv = (denom > 0.f) ? 1.f / denom : 0.f;

  bf16* arow = ao + ((size_t)(b * 2048 + jq * 128 + r) * 1024 + h * 64 + c0);
  const bf16* o2row = o2buf + ((size_t)(qtbh * 128 + r) * 64 + c0);
#pragma unroll
  for (int i = 0; i < 4; ++i) {
    const bf16x8 o1 = *(const bf16x8*)(arow + i * 8);
    const bf16x8 o2 = *(const bf16x8*)(o2row + i * 8);
    bf16x8 o;
#pragma unroll
    for (int j = 0; j < 8; ++j)
      o[j] = (bf16)((w1 * (float)o1[j] + w2 * (float)o2[j]) * linv);
    *(bf16x8*)(arow + i * 8) = o;
  }
}

// ---------------- last-row fix: ao[q=2047] = mean over s of V ----------------
__global__ __launch_bounds__(256) void vmean_kernel(const bf16* __restrict__ vt,
                                                    bf16* __restrict__ ao) {
  const int tid = threadIdx.x;
  const int lane = tid & 63, w = tid >> 6;
  const int gw = blockIdx.x * 4 + w;  // 0..2047 == bh*64 + d
  const int bh = gw >> 6, d = gw & 63;
  const int b = bh >> 4, h = bh & 15;
  const bf16x8* p = (const bf16x8*)(vt + (size_t)gw * 2048 + lane * 32);
  float s = 0.f;
#pragma unroll
  for (int i = 0; i < 4; ++i) {
    const bf16x8 v = p[i];
#pragma unroll
    for (int j = 0; j < 8; ++j) s += (float)v[j];
  }
  for (int off = 1; off < 64; off <<= 1) s += __shfl_xor(s, off);
  if (lane == 0)
    ao[(size_t)(b * 2048 + 2047) * 1024 + h * 64 + d] = (bf16)(s * (1.f / 2048.f));
}

extern "C" void kernel_launch(void* const* d_in, const int* in_sizes, int n_in,
                              void* d_out, int out_size, void* d_ws,
                              size_t ws_size, hipStream_t stream) {
  const float* x  = (const float*)d_in[0];
  const float* wq = (const float*)d_in[2];
  const float* bq = (const float*)d_in[3];
  const float* wk = (const float*)d_in[4];
  const float* bk = (const float*)d_in[5];
  const float* wv = (const float*)d_in[6];
  const float* bv = (const float*)d_in[7];
  const float* wo = (const float*)d_in[8];
  const float* bo = (const float*)d_in[9];
  float* out = (float*)d_out;

  if (ws_size < (size_t)25165824 * 2) return;  // need ~48 MiB of scratch

  bf16* ws    = (bf16*)d_ws;
  bf16* xb    = ws;                     // [4096][1024]; reused as partials
  bf16* wqkvT = xb + 4194304;           // [3072][1024]
  bf16* woT   = wqkvT + 3145728;        // [1024][1024]
  bf16* qfp   = woT + 1048576;          // [4096][1024] flat
  bf16* kfp   = qfp + 4194304;          // [4096][1024] flat
  bf16* vtp   = kfp + 4194304;          // [b][h][d][s]
  bf16* aop   = vtp + 4194304;          // [4096][1024] flat

  // partial scratch (xb is dead after the QKV GEMM):
  bf16*  o2buf = xb;                         // 8qt*32bh*128*64 bf16 = 4 MiB
  float* mlbuf = (float*)(xb + 2097152);     // 8*32*2*2*128 f32 = 512 KiB

  prep_kernel<<<5120, 256, 0, stream>>>(x, xb, wq, wk, wv, wo, wqkvT);

  gemm_bt<0><<<32 * 24, 256, 0, stream>>>(xb, wqkvT, bq, bk, bv, qfp, kfp, vtp,
                                          nullptr, 24);
  attn_kernel<<<768, 256, 0, stream>>>(qfp, kfp, vtp, aop, o2buf, mlbuf);
  vmean_kernel<<<512, 256, 0, stream>>>(vtp, aop);
  combine_kernel<<<256, 256, 0, stream>>>(o2buf, mlbuf, aop);
  gemm_bt<1><<<32 * 8, 256, 0, stream>>>(aop, woT, bo, nullptr, nullptr, nullptr,
                                         nullptr, nullptr, out, 8);
}